// Round 1
// baseline (432.673 us; speedup 1.0000x reference)
//
#include <hip/hip_runtime.h>
#include <stdint.h>

#define T_CTX 1024
#define DM 64
#define NH 2
#define HD 32
#define DFF 256
#define NVOCAB 8192

typedef int v4i __attribute__((ext_vector_type(4)));

__device__ __forceinline__ int clampi(int v, int lo, int hi){ return v<lo?lo:(v>hi?hi:v); }
__device__ __forceinline__ int wrap8(int v){ return ((v + 128) & 255) - 128; }
__device__ __forceinline__ int sdot4(int a, int b, int c){ return __builtin_amdgcn_sdot4(a, b, c, false); }

__device__ __forceinline__ int wave_reduce_add(int v){
  #pragma unroll
  for (int off = 1; off < 64; off <<= 1) v += __shfl_xor(v, off, 64);
  return v;
}
__device__ __forceinline__ int wave_reduce_max(int v){
  #pragma unroll
  for (int off = 1; off < 64; off <<= 1){ int o = __shfl_xor(v, off, 64); v = o > v ? o : v; }
  return v;
}

// rmsnorm_hw forward: exact integer pipeline; lane == channel (wave64 == DM)
__device__ __forceinline__ int rmsnorm_one(int xv, int g){
  int ss  = wave_reduce_add(xv * xv);
  int ms  = ss >> 6;                 // /64 == /d_model
  int lut = ms >> 6; if (lut > 255) lut = 255;
  int bc  = lut * 64 + 32;           // >= 32, so max(.,1) vacuous
  int inv = (int)__builtin_rint(16384.0 / __builtin_sqrt((double)bc)); // <= 2897 < 16383
  int p1  = (xv * inv) >> 8;         // arithmetic shift == floor
  int y   = (p1 * g) >> 10;
  return clampi(y, -128, 127);
}

// ---------------- prep: ternarize weights + quantize norm gammas ----------------
__global__ __launch_bounds__(256) void prep_weights(
    const float* __restrict__ qw, const float* __restrict__ kw, const float* __restrict__ vw,
    const float* __restrict__ ow, const float* __restrict__ uw, const float* __restrict__ dw,
    const float* __restrict__ anw, const float* __restrict__ fnw, const float* __restrict__ finw,
    int8_t* __restrict__ wt, int16_t* __restrict__ gq)
{
  int tid = threadIdx.x;
  int bid = blockIdx.x;
  if (bid < 24) {
    int layer = bid / 6, kind = bid % 6;
    const float* src; int n; int off;
    switch (kind) {
      case 0:  src = qw + layer*4096;  n = 4096;  off = 0;     break;
      case 1:  src = kw + layer*4096;  n = 4096;  off = 4096;  break;
      case 2:  src = vw + layer*4096;  n = 4096;  off = 8192;  break;
      case 3:  src = ow + layer*4096;  n = 4096;  off = 12288; break;
      case 4:  src = uw + layer*16384; n = 16384; off = 16384; break;
      default: src = dw + layer*16384; n = 16384; off = 32768; break;
    }
    __shared__ double sred[256];
    double s = 0.0;
    for (int i = tid; i < n; i += 256) s += (double)__builtin_fabsf(src[i]);
    sred[tid] = s; __syncthreads();
    for (int st = 128; st > 0; st >>= 1){ if (tid < st) sred[tid] += sred[tid + st]; __syncthreads(); }
    float fs = (float)(sred[0] / (double)n);
    if (fs < 1e-5f) fs = 1e-5f;
    int8_t* dst = wt + layer*49152 + off;
    for (int i = tid; i < n; i += 256) {
      int t = (int)__builtin_rintf(src[i] / fs);
      dst[i] = (int8_t)clampi(t, -1, 1);
    }
  } else {
    // 9 norms x 64 channels: 0..3 attn, 4..7 ffn, 8 final
    for (int i = tid; i < 576; i += 256) {
      int norm = i >> 6, c = i & 63;
      const float* wsrc = (norm < 4) ? (anw + norm*64) : (norm < 8) ? (fnw + (norm-4)*64) : finw;
      float wv = wsrc[c];
      float wc = wv < -2.0f ? -2.0f : (wv > 2.0f ? 2.0f : wv);
      gq[i] = (int16_t)clampi((int)__builtin_rintf(wc * 1024.0f), -32768, 32767);
    }
  }
}

// ---------------- prep: split Q5.10 embedding into hi/lo int8 planes ----------------
__global__ __launch_bounds__(256) void prep_emb_kernel(
    const float* __restrict__ tok_emb, int8_t* __restrict__ elo, int8_t* __restrict__ ehi)
{
  int i = blockIdx.x * 256 + threadIdx.x;   // grid covers NVOCAB*DM = 524288
  if (i < NVOCAB * DM) {
    int e  = clampi((int)__builtin_rintf(tok_emb[i] * 1024.0f), -32768, 32767);
    int l  = ((e + 128) & 255) - 128;       // signed low byte
    int hh = (e - l) >> 8;                  // e == 256*hh + l
    if (hh > 127) hh = 127;                 // unreachable for |emb| < 31.9 sigma
    elo[i] = (int8_t)l; ehi[i] = (int8_t)hh;
  }
}

// ---------------- per-token stage: [embed] -> [post: o-proj+res+FFN+res] -> [pre: norm+QKV] / [final norm]
__global__ __launch_bounds__(256) void token_stage(
    const int* __restrict__ tokens, const float* __restrict__ tok_emb, const float* __restrict__ pos_emb,
    int8_t* __restrict__ x, const int8_t* __restrict__ aArr,
    int8_t* __restrict__ qA, int8_t* __restrict__ kA, int8_t* __restrict__ vA,
    const int8_t* __restrict__ wt, const int16_t* __restrict__ gq, int8_t* __restrict__ xf,
    int do_embed, int post_layer, int pre_layer, int do_final)
{
  __shared__ int8_t sh8[4][DFF];
  int w = threadIdx.x >> 6, lane = threadIdx.x & 63;
  int t = blockIdx.x * 4 + w;             // token 0..4095
  int8_t* myS = sh8[w];
  int xv;
  if (do_embed) {
    int tok = tokens[t];
    int s = t & (T_CTX - 1);
    int tq = clampi((int)__builtin_rintf(tok_emb[tok*DM + lane] * 1024.0f), -32768, 32767);
    int pq = clampi((int)__builtin_rintf(pos_emb[s*DM + lane] * 1024.0f), -32768, 32767);
    xv = wrap8((tq + pq) >> 3);
  } else {
    xv = (int)x[t*DM + lane];
  }
  if (post_layer >= 0) {
    const int8_t* wtL = wt + post_layer*49152;
    myS[lane] = aArr[t*DM + lane];
    __syncthreads();
    { // o-projection (bitlinear), out channel = lane
      const int* a4 = (const int*)myS;
      const int* wo = (const int*)(wtL + 12288);
      int acc = 0;
      #pragma unroll
      for (int i = 0; i < 16; i++) acc = sdot4(a4[i], wo[lane*16 + i], acc);
      xv = wrap8(xv + clampi(acc >> 6, -128, 127));
    }
    __syncthreads();
    int h2 = rmsnorm_one(xv, (int)gq[(4 + post_layer)*DM + lane]);
    myS[lane] = (int8_t)h2;
    __syncthreads();
    int uv[4];
    { // up projection: 256 outputs, 4 per lane
      const int* h4 = (const int*)myS;
      const int* wu = (const int*)(wtL + 16384);
      #pragma unroll
      for (int jj = 0; jj < 4; jj++) {
        int j = jj*64 + lane;
        int acc = 0;
        #pragma unroll
        for (int i = 0; i < 16; i++) acc = sdot4(h4[i], wu[j*16 + i], acc);
        int u = clampi(acc >> 6, -128, 127);
        uv[jj] = u < 0 ? 0 : u;           // relu (then int8 clamp is identity)
      }
    }
    __syncthreads();
    #pragma unroll
    for (int jj = 0; jj < 4; jj++) myS[jj*64 + lane] = (int8_t)uv[jj];
    __syncthreads();
    { // down projection: in-dim 256
      const int* u4 = (const int*)myS;
      const int* wd = (const int*)(wtL + 32768);
      int acc = 0;
      #pragma unroll
      for (int i = 0; i < 64; i++) acc = sdot4(u4[i], wd[lane*64 + i], acc);
      xv = wrap8(xv + clampi(acc >> 6, -128, 127));
    }
    __syncthreads();
  }
  x[t*DM + lane] = (int8_t)xv;
  if (pre_layer >= 0) {
    int h = rmsnorm_one(xv, (int)gq[pre_layer*DM + lane]);
    myS[lane] = (int8_t)h;
    __syncthreads();
    const int8_t* wtL = wt + pre_layer*49152;
    const int* h4 = (const int*)myS;
    int b = t >> 10, s = t & (T_CTX - 1);
    int hh = lane >> 5, d = lane & 31;
    int8_t* dsts[3] = {qA, kA, vA};
    #pragma unroll
    for (int m = 0; m < 3; m++) {
      const int* wm = (const int*)(wtL + m*4096);
      int acc = 0;
      #pragma unroll
      for (int i = 0; i < 16; i++) acc = sdot4(h4[i], wm[lane*16 + i], acc);
      dsts[m][((b*NH + hh)*T_CTX + s)*HD + d] = (int8_t)clampi(acc >> 6, -128, 127);
    }
  }
  if (do_final) {
    int h = rmsnorm_one(xv, (int)gq[8*DM + lane]);
    xf[t*DM + lane] = (int8_t)h;
  }
}

// ---------------- attention: one wave per (b,h,q) row; exact hw_softmax ----------------
__global__ __launch_bounds__(256) void attn_kernel(
    const int8_t* __restrict__ qA, const int8_t* __restrict__ kA, const int8_t* __restrict__ vA,
    int8_t* __restrict__ aOut)
{
  __shared__ uint8_t sp[4][T_CTX];
  int w = threadIdx.x >> 6, lane = threadIdx.x & 63;
  int gid = blockIdx.x * 4 + w;           // 0..8191
  int qi  = gid & (T_CTX - 1);
  int bh  = gid >> 10;                    // 0..7 (b*2+h)
  const int8_t* qBase = qA + bh*(T_CTX*HD);
  const int8_t* kBase = kA + bh*(T_CTX*HD);
  const int8_t* vBase = vA + bh*(T_CTX*HD);
  const int4* qr = (const int4*)(qBase + qi*HD);
  int4 qa = qr[0], qb = qr[1];
  int sc[16];
  int mloc = -(1 << 30);
  #pragma unroll
  for (int j = 0; j < 16; j++) {
    int k = lane + j*64;
    int s;
    if (k <= qi) {
      const int4* kr = (const int4*)(kBase + k*HD);
      int4 ka = kr[0], kb = kr[1];
      int d = 0;
      d = sdot4(qa.x, ka.x, d); d = sdot4(qa.y, ka.y, d);
      d = sdot4(qa.z, ka.z, d); d = sdot4(qa.w, ka.w, d);
      d = sdot4(qb.x, kb.x, d); d = sdot4(qb.y, kb.y, d);
      d = sdot4(qb.z, kb.z, d); d = sdot4(qb.w, kb.w, d);
      s = (d * 45) >> 8;                  // floor; diag k==q gives s>=0 so the -32767 mask never wins
    } else s = -(1 << 30);
    sc[j] = s; if (s > mloc) mloc = s;
  }
  int m = wave_reduce_max(mloc);
  int ssum = 0;
  #pragma unroll
  for (int j = 0; j < 16; j++) {
    int k = lane + j*64;
    int e = 0;
    if (k <= qi) {
      int sh = sc[j] - m;                 // <= 0
      e = (sh >= -3) ? (256 + sh*64)
        : (sh >= -8) ? (64 + (sh + 3)*11)
        : (sh >= -24) ? (sh + 24) : 0;
    }
    sc[j] = e; ssum += e;
  }
  int s0 = wave_reduce_add(ssum); if (s0 < 1) s0 = 1;
  float sf = (float)s0;
  #pragma unroll
  for (int j = 0; j < 16; j++) {
    int k = lane + j*64;
    if (k <= qi) {
      int p = (int)__builtin_rintf((float)sc[j] / sf * 255.0f);  // same op order as reference
      sp[w][k] = (uint8_t)clampi(p, 0, 255);
    }
  }
  __syncthreads();
  // PV: lane -> (dim group d4 = (lane&7)*4, key chunk ch = lane>>3)
  int d4 = (lane & 7) * 4;
  int ch = lane >> 3;
  int a0 = 0, a1 = 0, a2 = 0, a3 = 0;
  for (int k = ch; k <= qi; k += 8) {
    int pv = (int)sp[w][k];
    int vv = *(const int*)(vBase + k*HD + d4);
    a0 += pv * ((vv << 24) >> 24);
    a1 += pv * ((vv << 16) >> 24);
    a2 += pv * ((vv <<  8) >> 24);
    a3 += pv * ( vv        >> 24);
  }
  #pragma unroll
  for (int off = 8; off < 64; off <<= 1) {
    a0 += __shfl_xor(a0, off, 64);
    a1 += __shfl_xor(a1, off, 64);
    a2 += __shfl_xor(a2, off, 64);
    a3 += __shfl_xor(a3, off, 64);
  }
  if (ch == 0) {
    int b = bh >> 1, h = bh & 1;
    int r0 = wrap8(a0 >> 8) & 255;
    int r1 = wrap8(a1 >> 8) & 255;
    int r2 = wrap8(a2 >> 8) & 255;
    int r3 = wrap8(a3 >> 8) & 255;
    int packed = r0 | (r1 << 8) | (r2 << 16) | (r3 << 24);
    *(int*)(aOut + (b*T_CTX + qi)*DM + h*HD + d4) = packed;
  }
}

// ---------------- logits: xf[4096x64] int8 x emb(hi/lo int8)[8192x64]^T via i8 MFMA ----------------
__global__ __launch_bounds__(256) void logits_kernel(
    const int8_t* __restrict__ xf, const int8_t* __restrict__ elo, const int8_t* __restrict__ ehi,
    float* __restrict__ out)
{
  int w = threadIdx.x >> 6, lane = threadIdx.x & 63;
  int m = lane & 15, quad = lane >> 4;
  int tokBase = blockIdx.y * 64 + w * 16;
  v4i A = *(const v4i*)(xf + (tokBase + m)*DM + quad*16);  // A[m=lane&15][k=quad*16+j]
  #pragma unroll
  for (int tile = 0; tile < 8; tile++) {
    int vocBase = blockIdx.x * 128 + tile * 16;
    v4i Blo = *(const v4i*)(elo + (vocBase + m)*DM + quad*16);
    v4i Bhi = *(const v4i*)(ehi + (vocBase + m)*DM + quad*16);
    v4i zero = {0, 0, 0, 0};
    v4i dLo = __builtin_amdgcn_mfma_i32_16x16x64_i8(A, Blo, zero, 0, 0, 0);
    v4i dHi = __builtin_amdgcn_mfma_i32_16x16x64_i8(A, Bhi, zero, 0, 0, 0);
    #pragma unroll
    for (int r = 0; r < 4; r++) {
      int val = dLo[r] + (dHi[r] << 8);                     // dot(x, 256*hi + lo), exact int32
      int row = tokBase + quad*4 + r;                       // C/D: row=(lane>>4)*4+reg
      int col = vocBase + m;                                // col=lane&15
      out[row*NVOCAB + col] = (float)val * 1.220703125e-4f; // * 2^-13 == D^-0.5/1024
    }
  }
}

extern "C" void kernel_launch(void* const* d_in, const int* in_sizes, int n_in,
                              void* d_out, int out_size, void* d_ws, size_t ws_size,
                              hipStream_t stream)
{
  const int*   tokens  = (const int*)d_in[0];
  const float* tok_emb = (const float*)d_in[1];
  const float* pos_emb = (const float*)d_in[2];
  const float* attn_nw = (const float*)d_in[3];
  const float* q_w     = (const float*)d_in[4];
  const float* k_w     = (const float*)d_in[5];
  const float* v_w     = (const float*)d_in[6];
  const float* o_w     = (const float*)d_in[7];
  const float* ff_nw   = (const float*)d_in[8];
  const float* up_w    = (const float*)d_in[9];
  const float* dn_w    = (const float*)d_in[10];
  const float* fin_nw  = (const float*)d_in[11];
  float* out = (float*)d_out;
  char* ws = (char*)d_ws;

  int8_t*  x   = (int8_t*)(ws + 0);        // 4096*64
  int8_t*  a   = (int8_t*)(ws + 262144);   // 4096*64 attn output (token-major)
  int8_t*  qA  = (int8_t*)(ws + 524288);   // [b][h][t][d]
  int8_t*  kA  = (int8_t*)(ws + 786432);
  int8_t*  vA  = (int8_t*)(ws + 1048576);
  int8_t*  wt  = (int8_t*)(ws + 1310720);  // 4 layers * 49152 ternary weights
  int8_t*  elo = (int8_t*)(ws + 1507328);  // 8192*64
  int8_t*  ehi = (int8_t*)(ws + 2031616);  // 8192*64
  int16_t* gq  = (int16_t*)(ws + 2555904); // 9*64
  int8_t*  xf  = (int8_t*)(ws + 2560000);  // 4096*64

  prep_weights<<<25, 256, 0, stream>>>(q_w, k_w, v_w, o_w, up_w, dn_w, attn_nw, ff_nw, fin_nw, wt, gq);
  prep_emb_kernel<<<2048, 256, 0, stream>>>(tok_emb, elo, ehi);
  // embed + pre layer 0
  token_stage<<<1024, 256, 0, stream>>>(tokens, tok_emb, pos_emb, x, a, qA, kA, vA, wt, gq, xf,
                                        1, -1, 0, 0);
  for (int L = 0; L < 4; L++) {
    attn_kernel<<<2048, 256, 0, stream>>>(qA, kA, vA, a);
    int pre = (L < 3) ? (L + 1) : -1;
    int fin = (L == 3) ? 1 : 0;
    token_stage<<<1024, 256, 0, stream>>>(tokens, tok_emb, pos_emb, x, a, qA, kA, vA, wt, gq, xf,
                                          0, L, pre, fin);
  }
  logits_kernel<<<dim3(64, 64), 256, 0, stream>>>(xf, elo, ehi, out);
}

// Round 2
// 358.669 us; speedup vs baseline: 1.2063x; 1.2063x over previous
//
#include <hip/hip_runtime.h>
#include <stdint.h>

#define T_CTX 1024
#define DM 64
#define NH 2
#define HD 32
#define DFF 256
#define NVOCAB 8192

typedef int v4i __attribute__((ext_vector_type(4)));

__device__ __forceinline__ int clampi(int v, int lo, int hi){ return v<lo?lo:(v>hi?hi:v); }
__device__ __forceinline__ int wrap8(int v){ return ((v + 128) & 255) - 128; }
__device__ __forceinline__ int sdot4(int a, int b, int c){ return __builtin_amdgcn_sdot4(a, b, c, false); }

__device__ __forceinline__ int wave_reduce_add(int v){
  #pragma unroll
  for (int off = 1; off < 64; off <<= 1) v += __shfl_xor(v, off, 64);
  return v;
}
__device__ __forceinline__ int wave_reduce_max(int v){
  #pragma unroll
  for (int off = 1; off < 64; off <<= 1){ int o = __shfl_xor(v, off, 64); v = o > v ? o : v; }
  return v;
}

// rmsnorm_hw forward: exact integer pipeline; lane == channel (wave64 == DM)
__device__ __forceinline__ int rmsnorm_one(int xv, int g){
  int ss  = wave_reduce_add(xv * xv);
  int ms  = ss >> 6;                 // /64 == /d_model
  int lut = ms >> 6; if (lut > 255) lut = 255;
  int bc  = lut * 64 + 32;           // >= 32, so max(.,1) vacuous
  int inv = (int)__builtin_rint(16384.0 / __builtin_sqrt((double)bc)); // <= 2897 < 16383
  int p1  = (xv * inv) >> 8;         // arithmetic shift == floor
  int y   = (p1 * g) >> 10;
  return clampi(y, -128, 127);
}

// ---------------- prep: ternarize weights + quantize norm gammas ----------------
__global__ __launch_bounds__(256) void prep_weights(
    const float* __restrict__ qw, const float* __restrict__ kw, const float* __restrict__ vw,
    const float* __restrict__ ow, const float* __restrict__ uw, const float* __restrict__ dw,
    const float* __restrict__ anw, const float* __restrict__ fnw, const float* __restrict__ finw,
    int8_t* __restrict__ wt, int16_t* __restrict__ gq)
{
  int tid = threadIdx.x;
  int bid = blockIdx.x;
  if (bid < 24) {
    int layer = bid / 6, kind = bid % 6;
    const float* src; int n; int off;
    switch (kind) {
      case 0:  src = qw + layer*4096;  n = 4096;  off = 0;     break;
      case 1:  src = kw + layer*4096;  n = 4096;  off = 4096;  break;
      case 2:  src = vw + layer*4096;  n = 4096;  off = 8192;  break;
      case 3:  src = ow + layer*4096;  n = 4096;  off = 12288; break;
      case 4:  src = uw + layer*16384; n = 16384; off = 16384; break;
      default: src = dw + layer*16384; n = 16384; off = 32768; break;
    }
    __shared__ double sred[256];
    double s = 0.0;
    for (int i = tid; i < n; i += 256) s += (double)__builtin_fabsf(src[i]);
    sred[tid] = s; __syncthreads();
    for (int st = 128; st > 0; st >>= 1){ if (tid < st) sred[tid] += sred[tid + st]; __syncthreads(); }
    float fs = (float)(sred[0] / (double)n);
    if (fs < 1e-5f) fs = 1e-5f;
    int8_t* dst = wt + layer*49152 + off;
    for (int i = tid; i < n; i += 256) {
      int t = (int)__builtin_rintf(src[i] / fs);
      dst[i] = (int8_t)clampi(t, -1, 1);
    }
  } else {
    // 9 norms x 64 channels: 0..3 attn, 4..7 ffn, 8 final
    for (int i = tid; i < 576; i += 256) {
      int norm = i >> 6, c = i & 63;
      const float* wsrc = (norm < 4) ? (anw + norm*64) : (norm < 8) ? (fnw + (norm-4)*64) : finw;
      float wv = wsrc[c];
      float wc = wv < -2.0f ? -2.0f : (wv > 2.0f ? 2.0f : wv);
      gq[i] = (int16_t)clampi((int)__builtin_rintf(wc * 1024.0f), -32768, 32767);
    }
  }
}

// ---------------- prep: split Q5.10 embedding into hi/lo int8 planes ----------------
__global__ __launch_bounds__(256) void prep_emb_kernel(
    const float* __restrict__ tok_emb, int8_t* __restrict__ elo, int8_t* __restrict__ ehi)
{
  int i = blockIdx.x * 256 + threadIdx.x;   // grid covers NVOCAB*DM = 524288
  if (i < NVOCAB * DM) {
    int e  = clampi((int)__builtin_rintf(tok_emb[i] * 1024.0f), -32768, 32767);
    int l  = ((e + 128) & 255) - 128;       // signed low byte
    int hh = (e - l) >> 8;                  // e == 256*hh + l
    if (hh > 127) hh = 127;                 // unreachable for |emb| < 31.9 sigma
    elo[i] = (int8_t)l; ehi[i] = (int8_t)hh;
  }
}

// ---------------- per-token stage: [embed] -> [post: o-proj+res+FFN+res] -> [pre: norm+QKV] / [final norm]
// V is written TRANSPOSED: vT[bh][d][t] so attn can stage V^T rows coalesced.
__global__ __launch_bounds__(256) void token_stage(
    const int* __restrict__ tokens, const float* __restrict__ tok_emb, const float* __restrict__ pos_emb,
    int8_t* __restrict__ x, const int8_t* __restrict__ aArr,
    int8_t* __restrict__ qA, int8_t* __restrict__ kA, int8_t* __restrict__ vT,
    const int8_t* __restrict__ wt, const int16_t* __restrict__ gq, int8_t* __restrict__ xf,
    int do_embed, int post_layer, int pre_layer, int do_final)
{
  __shared__ int8_t sh8[4][DFF];
  int w = threadIdx.x >> 6, lane = threadIdx.x & 63;
  int t = blockIdx.x * 4 + w;             // token 0..4095
  int8_t* myS = sh8[w];
  int xv;
  if (do_embed) {
    int tok = tokens[t];
    int s = t & (T_CTX - 1);
    int tq = clampi((int)__builtin_rintf(tok_emb[tok*DM + lane] * 1024.0f), -32768, 32767);
    int pq = clampi((int)__builtin_rintf(pos_emb[s*DM + lane] * 1024.0f), -32768, 32767);
    xv = wrap8((tq + pq) >> 3);
  } else {
    xv = (int)x[t*DM + lane];
  }
  if (post_layer >= 0) {
    const int8_t* wtL = wt + post_layer*49152;
    myS[lane] = aArr[t*DM + lane];
    __syncthreads();
    { // o-projection (bitlinear), out channel = lane
      const int* a4 = (const int*)myS;
      const int* wo = (const int*)(wtL + 12288);
      int acc = 0;
      #pragma unroll
      for (int i = 0; i < 16; i++) acc = sdot4(a4[i], wo[lane*16 + i], acc);
      xv = wrap8(xv + clampi(acc >> 6, -128, 127));
    }
    __syncthreads();
    int h2 = rmsnorm_one(xv, (int)gq[(4 + post_layer)*DM + lane]);
    myS[lane] = (int8_t)h2;
    __syncthreads();
    int uv[4];
    { // up projection: 256 outputs, 4 per lane
      const int* h4 = (const int*)myS;
      const int* wu = (const int*)(wtL + 16384);
      #pragma unroll
      for (int jj = 0; jj < 4; jj++) {
        int j = jj*64 + lane;
        int acc = 0;
        #pragma unroll
        for (int i = 0; i < 16; i++) acc = sdot4(h4[i], wu[j*16 + i], acc);
        int u = clampi(acc >> 6, -128, 127);
        uv[jj] = u < 0 ? 0 : u;           // relu (then int8 clamp is identity)
      }
    }
    __syncthreads();
    #pragma unroll
    for (int jj = 0; jj < 4; jj++) myS[jj*64 + lane] = (int8_t)uv[jj];
    __syncthreads();
    { // down projection: in-dim 256
      const int* u4 = (const int*)myS;
      const int* wd = (const int*)(wtL + 32768);
      int acc = 0;
      #pragma unroll
      for (int i = 0; i < 64; i++) acc = sdot4(u4[i], wd[lane*64 + i], acc);
      xv = wrap8(xv + clampi(acc >> 6, -128, 127));
    }
    __syncthreads();
  }
  x[t*DM + lane] = (int8_t)xv;
  if (pre_layer >= 0) {
    int h = rmsnorm_one(xv, (int)gq[pre_layer*DM + lane]);
    myS[lane] = (int8_t)h;
    __syncthreads();
    const int8_t* wtL = wt + pre_layer*49152;
    const int* h4 = (const int*)myS;
    int b = t >> 10, s = t & (T_CTX - 1);
    int hh = lane >> 5, d = lane & 31;
    int bhh = b*NH + hh;
    { // q
      const int* wm = (const int*)(wtL + 0);
      int acc = 0;
      #pragma unroll
      for (int i = 0; i < 16; i++) acc = sdot4(h4[i], wm[lane*16 + i], acc);
      qA[(bhh*T_CTX + s)*HD + d] = (int8_t)clampi(acc >> 6, -128, 127);
    }
    { // k
      const int* wm = (const int*)(wtL + 4096);
      int acc = 0;
      #pragma unroll
      for (int i = 0; i < 16; i++) acc = sdot4(h4[i], wm[lane*16 + i], acc);
      kA[(bhh*T_CTX + s)*HD + d] = (int8_t)clampi(acc >> 6, -128, 127);
    }
    { // v -> transposed layout
      const int* wm = (const int*)(wtL + 8192);
      int acc = 0;
      #pragma unroll
      for (int i = 0; i < 16; i++) acc = sdot4(h4[i], wm[lane*16 + i], acc);
      vT[(bhh*HD + d)*T_CTX + s] = (int8_t)clampi(acc >> 6, -128, 127);
    }
  }
  if (do_final) {
    int h = rmsnorm_one(xv, (int)gq[8*DM + lane]);
    xf[t*DM + lane] = (int8_t)h;
  }
}

// ---------------- attention: 4 q-rows per block (one bh), V^T staged in LDS, sdot4 PV ----------------
__global__ __launch_bounds__(256) void attn_kernel(
    const int8_t* __restrict__ qA, const int8_t* __restrict__ kA, const int8_t* __restrict__ vT,
    int8_t* __restrict__ aOut)
{
  __shared__ int vt32[32*257];   // V^T [d][k/4 words], stride 257 -> bank=(d+c)&31
  __shared__ int sp32[4][256];   // probs, one 1024-byte row per wave
  int w = threadIdx.x >> 6, lane = threadIdx.x & 63;
  int bh = blockIdx.x & 7, qblk = blockIdx.x >> 3;  // qblk 0 first => heaviest rows dispatch first
  int qi = 1023 - 4*qblk - w;
  int b = bh >> 1, h = bh & 1;
  const int8_t* qBase = qA + bh*(T_CTX*HD);
  const int8_t* kBase = kA + bh*(T_CTX*HD);
  const int8_t* vTbh  = vT + bh*(HD*T_CTX);

  // stage V^T into LDS: wave w handles d = 4r+w; lanes cover a row's 64 int4s
  #pragma unroll
  for (int r = 0; r < 8; r++) {
    int d = r*4 + w;
    int4 v = *(const int4*)(vTbh + d*T_CTX + lane*16);
    int* dst = vt32 + d*257 + lane*4;
    dst[0] = v.x; dst[1] = v.y; dst[2] = v.z; dst[3] = v.w;
  }

  // ---- QK^T row + hw softmax (exact) ----
  const int4* qr = (const int4*)(qBase + qi*HD);
  int4 qa = qr[0], qb = qr[1];
  int sc[16];
  int mloc = -(1 << 30);
  #pragma unroll
  for (int j = 0; j < 16; j++) {
    int k = lane + j*64;
    int s;
    if (k <= qi) {
      const int4* kr = (const int4*)(kBase + k*HD);
      int4 ka = kr[0], kb = kr[1];
      int d = 0;
      d = sdot4(qa.x, ka.x, d); d = sdot4(qa.y, ka.y, d);
      d = sdot4(qa.z, ka.z, d); d = sdot4(qa.w, ka.w, d);
      d = sdot4(qb.x, kb.x, d); d = sdot4(qb.y, kb.y, d);
      d = sdot4(qb.z, kb.z, d); d = sdot4(qb.w, kb.w, d);
      s = (d * 45) >> 8;                  // floor; diag k==q gives s>=0 so the -32767 mask never wins
    } else s = -(1 << 30);
    sc[j] = s; if (s > mloc) mloc = s;
  }
  int m = wave_reduce_max(mloc);
  int ssum = 0;
  #pragma unroll
  for (int j = 0; j < 16; j++) {
    int k = lane + j*64;
    int e = 0;
    if (k <= qi) {
      int sh = sc[j] - m;                 // <= 0
      e = (sh >= -3) ? (256 + sh*64)
        : (sh >= -8) ? (64 + (sh + 3)*11)
        : (sh >= -24) ? (sh + 24) : 0;
    }
    sc[j] = e; ssum += e;
  }
  int s0 = wave_reduce_add(ssum); if (s0 < 1) s0 = 1;
  float sf = (float)s0;
  uint8_t* spb = (uint8_t*)sp32[w];
  #pragma unroll
  for (int j = 0; j < 16; j++) {
    int k = lane + j*64;
    // e==0 for k>qi so the same formula writes the zero padding
    int p = (int)__builtin_rintf((float)sc[j] / sf * 255.0f);
    spb[k] = (uint8_t)clampi(p, 0, 255);
  }
  __syncthreads();   // vt32 + this wave's prob row visible

  // ---- PV via packed sdot4: p = 2*(p>>1) + (p&1) ----
  int dg = lane & 7, kc = lane >> 3;
  const int* vr0 = vt32 + (dg*4 + 0)*257;
  const int* vr1 = vt32 + (dg*4 + 1)*257;
  const int* vr2 = vt32 + (dg*4 + 2)*257;
  const int* vr3 = vt32 + (dg*4 + 3)*257;
  const int* spw = sp32[w];
  int hi0=0, hi1=0, hi2=0, hi3=0, lo0=0, lo1=0, lo2=0, lo3=0;
  int cmax = qi >> 2;
  for (int c = kc; c <= cmax; c += 8) {
    int p4 = spw[c];
    int ph = (p4 >> 1) & 0x7f7f7f7f;
    int pl = p4 & 0x01010101;
    int v0 = vr0[c], v1 = vr1[c], v2 = vr2[c], v3 = vr3[c];
    hi0 = sdot4(ph, v0, hi0); lo0 = sdot4(pl, v0, lo0);
    hi1 = sdot4(ph, v1, hi1); lo1 = sdot4(pl, v1, lo1);
    hi2 = sdot4(ph, v2, hi2); lo2 = sdot4(pl, v2, lo2);
    hi3 = sdot4(ph, v3, hi3); lo3 = sdot4(pl, v3, lo3);
  }
  int a0 = 2*hi0 + lo0, a1 = 2*hi1 + lo1, a2 = 2*hi2 + lo2, a3 = 2*hi3 + lo3;
  #pragma unroll
  for (int off = 8; off < 64; off <<= 1) {
    a0 += __shfl_xor(a0, off, 64);
    a1 += __shfl_xor(a1, off, 64);
    a2 += __shfl_xor(a2, off, 64);
    a3 += __shfl_xor(a3, off, 64);
  }
  if (kc == 0) {
    int r0 = wrap8(a0 >> 8) & 255;
    int r1 = wrap8(a1 >> 8) & 255;
    int r2 = wrap8(a2 >> 8) & 255;
    int r3 = wrap8(a3 >> 8) & 255;
    int packed = r0 | (r1 << 8) | (r2 << 16) | (r3 << 24);
    *(int*)(aOut + (b*T_CTX + qi)*DM + h*HD + dg*4) = packed;
  }
}

// ---------------- logits: xf[4096x64] int8 x emb(hi/lo int8)[8192x64]^T via i8 MFMA ----------------
__global__ __launch_bounds__(256) void logits_kernel(
    const int8_t* __restrict__ xf, const int8_t* __restrict__ elo, const int8_t* __restrict__ ehi,
    float* __restrict__ out)
{
  int w = threadIdx.x >> 6, lane = threadIdx.x & 63;
  int m = lane & 15, quad = lane >> 4;
  int tokBase = blockIdx.y * 64 + w * 16;
  v4i A = *(const v4i*)(xf + (tokBase + m)*DM + quad*16);  // A[m=lane&15][k=quad*16+j]
  #pragma unroll
  for (int tile = 0; tile < 8; tile++) {
    int vocBase = blockIdx.x * 128 + tile * 16;
    v4i Blo = *(const v4i*)(elo + (vocBase + m)*DM + quad*16);
    v4i Bhi = *(const v4i*)(ehi + (vocBase + m)*DM + quad*16);
    v4i zero = {0, 0, 0, 0};
    v4i dLo = __builtin_amdgcn_mfma_i32_16x16x64_i8(A, Blo, zero, 0, 0, 0);
    v4i dHi = __builtin_amdgcn_mfma_i32_16x16x64_i8(A, Bhi, zero, 0, 0, 0);
    #pragma unroll
    for (int r = 0; r < 4; r++) {
      int val = dLo[r] + (dHi[r] << 8);                     // dot(x, 256*hi + lo), exact int32
      int row = tokBase + quad*4 + r;                       // C/D: row=(lane>>4)*4+reg
      int col = vocBase + m;                                // col=lane&15
      out[row*NVOCAB + col] = (float)val * 1.220703125e-4f; // * 2^-13 == D^-0.5/1024
    }
  }
}

extern "C" void kernel_launch(void* const* d_in, const int* in_sizes, int n_in,
                              void* d_out, int out_size, void* d_ws, size_t ws_size,
                              hipStream_t stream)
{
  const int*   tokens  = (const int*)d_in[0];
  const float* tok_emb = (const float*)d_in[1];
  const float* pos_emb = (const float*)d_in[2];
  const float* attn_nw = (const float*)d_in[3];
  const float* q_w     = (const float*)d_in[4];
  const float* k_w     = (const float*)d_in[5];
  const float* v_w     = (const float*)d_in[6];
  const float* o_w     = (const float*)d_in[7];
  const float* ff_nw   = (const float*)d_in[8];
  const float* up_w    = (const float*)d_in[9];
  const float* dn_w    = (const float*)d_in[10];
  const float* fin_nw  = (const float*)d_in[11];
  float* out = (float*)d_out;
  char* ws = (char*)d_ws;

  int8_t*  x   = (int8_t*)(ws + 0);        // 4096*64
  int8_t*  a   = (int8_t*)(ws + 262144);   // 4096*64 attn output (token-major)
  int8_t*  qA  = (int8_t*)(ws + 524288);   // [b][h][t][d]
  int8_t*  kA  = (int8_t*)(ws + 786432);   // [b][h][t][d]
  int8_t*  vT  = (int8_t*)(ws + 1048576);  // [b][h][d][t]  (transposed V)
  int8_t*  wt  = (int8_t*)(ws + 1310720);  // 4 layers * 49152 ternary weights
  int8_t*  elo = (int8_t*)(ws + 1507328);  // 8192*64
  int8_t*  ehi = (int8_t*)(ws + 2031616);  // 8192*64
  int16_t* gq  = (int16_t*)(ws + 2555904); // 9*64
  int8_t*  xf  = (int8_t*)(ws + 2560000);  // 4096*64

  prep_weights<<<25, 256, 0, stream>>>(q_w, k_w, v_w, o_w, up_w, dn_w, attn_nw, ff_nw, fin_nw, wt, gq);
  prep_emb_kernel<<<2048, 256, 0, stream>>>(tok_emb, elo, ehi);
  // embed + pre layer 0
  token_stage<<<1024, 256, 0, stream>>>(tokens, tok_emb, pos_emb, x, a, qA, kA, vT, wt, gq, xf,
                                        1, -1, 0, 0);
  for (int L = 0; L < 4; L++) {
    attn_kernel<<<2048, 256, 0, stream>>>(qA, kA, vT, a);
    int pre = (L < 3) ? (L + 1) : -1;
    int fin = (L == 3) ? 1 : 0;
    token_stage<<<1024, 256, 0, stream>>>(tokens, tok_emb, pos_emb, x, a, qA, kA, vT, wt, gq, xf,
                                          0, L, pre, fin);
  }
  logits_kernel<<<dim3(64, 64), 256, 0, stream>>>(xf, elo, ehi, out);
}